// Round 4
// baseline (383.633 us; speedup 1.0000x reference)
//
#include <hip/hip_runtime.h>
#include <hip/hip_bf16.h>
#include <cstdint>

// Problem constants
#define NTOK 8192
#define DIN  1024
#define DOUT 1024
#define NEXP 8

typedef __attribute__((ext_vector_type(8)))  __bf16 bf16x8;
typedef __attribute__((ext_vector_type(4)))  float  f32x4;

__device__ __forceinline__ unsigned short f2bf(float f) {
    unsigned int u = __builtin_bit_cast(unsigned int, f);
    u += 0x7FFFu + ((u >> 16) & 1u);   // round-to-nearest-even
    return (unsigned short)(u >> 16);
}

__device__ __forceinline__ void cp16(const void* gsrc, void* ldst) {
    __builtin_amdgcn_global_load_lds(
        (const __attribute__((address_space(1))) void*)gsrc,
        (__attribute__((address_space(3))) void*)ldst,
        16, 0, 0);
}

// ---------------------------------------------------------------------------
// Prep kernel (unchanged from R3 — prep time is harness-dominated, see R3
// post-mortem: non-GEMM total is ~112us regardless of prep structure):
//   blocks [0, 2048):     We [e][k][o] fp32 -> WebT [e][o][k] bf16
//   blocks [2048, 2304):  gate softmax(x@Wg+bg) + x -> bf16
// ---------------------------------------------------------------------------
__global__ __launch_bounds__(256) void prep_kernel(
    const float* __restrict__ x, const float* __restrict__ We,
    const float* __restrict__ Wg, const float* __restrict__ bg,
    unsigned short* __restrict__ xb, unsigned short* __restrict__ wt,
    float* __restrict__ g)
{
    __shared__ float smem[12416];

    int t = threadIdx.x;

    if (blockIdx.x < 2048) {
        unsigned short* tile = (unsigned short*)smem;   // [64][72]
        int b = blockIdx.x;
        int e  = b >> 8;
        int kt = (b >> 4) & 15;
        int ot = b & 15;

        const float* src = We + ((size_t)e << 20) + (size_t)(kt * 64) * DOUT + ot * 64;
        unsigned short* dst = wt + ((size_t)e << 20) + (size_t)(ot * 64) * DIN + kt * 64;

        int kl = t >> 2;
        int og = (t & 3) * 16;
#pragma unroll
        for (int c = 0; c < 4; ++c) {
            int o = og + c * 4;
            float4 v = *(const float4*)&src[(size_t)kl * DOUT + o];
            ushort4 u;
            u.x = f2bf(v.x); u.y = f2bf(v.y); u.z = f2bf(v.z); u.w = f2bf(v.w);
            *(ushort4*)&tile[kl * 72 + o] = u;
        }
        __syncthreads();
        int ol = t >> 2;
        int kg = (t & 3) * 16;
        unsigned short tmp[16];
#pragma unroll
        for (int i = 0; i < 16; ++i) tmp[i] = tile[(kg + i) * 72 + ol];
        *(uint4*)&dst[(size_t)ol * DIN + kg]     = *(uint4*)&tmp[0];
        *(uint4*)&dst[(size_t)ol * DIN + kg + 8] = *(uint4*)&tmp[8];
    } else {
        float* WgL = smem;          // [8][1024] transposed Wg
        float* xL  = smem + 8192;   // [32][132] x chunk
        int n0 = (blockIdx.x - 2048) * 32;

#pragma unroll
        for (int q = 0; q < 8; ++q) {
            int fidx = q * 256 + t;
            int k  = fidx >> 1;
            int eh = (fidx & 1) * 4;
            float4 v = *(const float4*)&Wg[(size_t)k * 8 + eh];
            WgL[(eh + 0) * 1024 + k] = v.x;
            WgL[(eh + 1) * 1024 + k] = v.y;
            WgL[(eh + 2) * 1024 + k] = v.z;
            WgL[(eh + 3) * 1024 + k] = v.w;
        }

        int tt = t & 31;
        int e  = t >> 5;
        float acc = 0.f;

        for (int c = 0; c < 8; ++c) {
            int kb = c * 128;
#pragma unroll
            for (int q = 0; q < 4; ++q) {
                int fidx = q * 256 + t;
                int row = fidx >> 5;
                int kk  = (fidx & 31) * 4;
                float4 v = *(const float4*)&x[(size_t)(n0 + row) * DIN + kb + kk];
                ushort4 u;
                u.x = f2bf(v.x); u.y = f2bf(v.y); u.z = f2bf(v.z); u.w = f2bf(v.w);
                *(ushort4*)&xb[(size_t)(n0 + row) * DIN + kb + kk] = u;
                *(float4*)&xL[row * 132 + kk] = v;
            }
            __syncthreads();
#pragma unroll
            for (int kk = 0; kk < 128; kk += 4) {
                float4 xv = *(const float4*)&xL[tt * 132 + kk];
                float4 wv = *(const float4*)&WgL[e * 1024 + kb + kk];
                acc += xv.x * wv.x + xv.y * wv.y + xv.z * wv.z + xv.w * wv.w;
            }
            __syncthreads();
        }

        float* lg = xL;
        lg[tt * 8 + e] = acc + bg[e];
        __syncthreads();
        if (t < 32) {
            float l[8];
#pragma unroll
            for (int i = 0; i < 8; ++i) l[i] = lg[t * 8 + i];
            float m = l[0];
#pragma unroll
            for (int i = 1; i < 8; ++i) m = fmaxf(m, l[i]);
            float s = 0.f;
#pragma unroll
            for (int i = 0; i < 8; ++i) { l[i] = __expf(l[i] - m); s += l[i]; }
            float inv = 1.0f / s;
            float4 p0 = make_float4(l[0]*inv, l[1]*inv, l[2]*inv, l[3]*inv);
            float4 p1 = make_float4(l[4]*inv, l[5]*inv, l[6]*inv, l[7]*inv);
            *(float4*)&g[(size_t)(n0 + tt) * 8]     = p0;
            *(float4*)&g[(size_t)(n0 + tt) * 8 + 4] = p1;
        }
    }
}

// ---------------------------------------------------------------------------
// Main MoE GEMM — R2's verified geometry (16x16x32 MFMA, BK=64, XOR swizzle,
// XCD bm-slab) + EXPERT PAIRING: stage lA once + lB0 + lB1 per K-window;
// each A fragment feeds both experts' MFMAs.
//   - LDS fragment reads: 12 per 32 MFMA (was 8/16) -> 0.375 KB/MFMA
//   - A staged 4x instead of 8x -> L2 feed 8->6 MB/CU, LDS writes 8->6 MB
//   - barrier pairs per block: 128 -> 64
// R3's 32x32 MFMA reverted: its fragment pattern 4-way bank-conflicts
// (1.68e7 measured) and the MFMA shape doesn't change LDS bytes/FLOP.
// Regs: acc0+acc1+outAcc = 192 (AGPR) + ~120 VGPR, within the 512/wave
// budget at 2 waves/SIMD -> occupancy stays 2 blocks/CU (LDS 56KB*2 <= 160).
// ---------------------------------------------------------------------------
__global__ __launch_bounds__(256, 2) void moe_gemm_kernel(
    const unsigned short* __restrict__ xb,   // [NTOK][DIN] bf16
    const unsigned short* __restrict__ wt,   // [E][DOUT][DIN] bf16
    const float* __restrict__ g,             // [NTOK][E]
    const float* __restrict__ be,            // [E][DOUT]
    float* __restrict__ out)                 // [NTOK][DOUT]
{
    __shared__ unsigned short lA [128 * 64];   // 16 KB
    __shared__ unsigned short lB0[128 * 64];   // 16 KB
    __shared__ unsigned short lB1[128 * 64];   // 16 KB
    __shared__ float lG[128 * 8];              // 4 KB
    __shared__ float lBias[8 * 128];           // 4 KB

    int bid = blockIdx.x;
    int bm = (bid & 7) * 8 + ((bid >> 3) & 7);   // 0..63, XCD-local A slab
    int bn = bid >> 6;                            // 0..7
    int tid = threadIdx.x;
    int lane = tid & 63;
    int wave = tid >> 6;
    int wm = wave >> 1;        // 0..1
    int wn = wave & 1;         // 0..1

    // stage gate block [128 rows][8 experts] and bias block [8][128 cols]
    {
        *(float4*)&lG[tid * 4] = *(const float4*)&g[(size_t)(bm * 128) * 8 + tid * 4];
#pragma unroll
        for (int q = 0; q < 4; ++q) {
            int idx = q * 256 + tid;
            lBias[idx] = be[(size_t)(idx >> 7) * DOUT + bn * 128 + (idx & 127)];
        }
    }

    f32x4 outAcc[4][4] = {};

    const unsigned short* aBase = xb + (size_t)(bm * 128) * DIN;
    const unsigned short* bBase0 = wt + (size_t)(bn * 128) * DIN;

    int rowS = wave * 8 + (lane >> 3);                    // staging row in 32-row group
    int k8   = (((lane & 7) ^ (lane >> 3)) * 8);          // swizzled source k offset
    int rA   = lane & 15;                                 // fragment row/col
    int swz  = rA & 7;

    for (int ep = 0; ep < 4; ++ep) {
        f32x4 acc0[4][4] = {};
        f32x4 acc1[4][4] = {};
        const unsigned short* b0Base = bBase0 + ((size_t)(2 * ep) << 20);
        const unsigned short* b1Base = b0Base + (1u << 20);

        for (int kt = 0; kt < 16; ++kt) {
            int kb = kt * 64;
            __syncthreads();
#pragma unroll
            for (int j = 0; j < 4; ++j) {
                int row = j * 32 + rowS;
                size_t so = (size_t)row * DIN + kb + k8;
                cp16(aBase  + so, &lA [j * 2048 + wave * 512]);
                cp16(b0Base + so, &lB0[j * 2048 + wave * 512]);
                cp16(b1Base + so, &lB1[j * 2048 + wave * 512]);
            }
            __syncthreads();
#pragma unroll
            for (int ks = 0; ks < 2; ++ks) {
                int kc = ks * 4 + (lane >> 4);            // logical k-chunk 0..7
                int kp = (kc ^ swz) * 8;                  // swizzled physical offset
                bf16x8 af[4], b0f[4], b1f[4];
#pragma unroll
                for (int i = 0; i < 4; ++i)
                    af[i] = *(const bf16x8*)&lA[(wm * 64 + i * 16 + rA) * 64 + kp];
#pragma unroll
                for (int j = 0; j < 4; ++j) {
                    b0f[j] = *(const bf16x8*)&lB0[(wn * 64 + j * 16 + rA) * 64 + kp];
                    b1f[j] = *(const bf16x8*)&lB1[(wn * 64 + j * 16 + rA) * 64 + kp];
                }
#pragma unroll
                for (int i = 0; i < 4; ++i)
#pragma unroll
                    for (int j = 0; j < 4; ++j) {
                        acc0[i][j] = __builtin_amdgcn_mfma_f32_16x16x32_bf16(
                            af[i], b0f[j], acc0[i][j], 0, 0, 0);
                        acc1[i][j] = __builtin_amdgcn_mfma_f32_16x16x32_bf16(
                            af[i], b1f[j], acc1[i][j], 0, 0, 0);
                    }
            }
        }

        // merge both experts: outAcc += g[row,e] * (acc + be[e,col])
#pragma unroll
        for (int h = 0; h < 2; ++h) {
            int e = 2 * ep + h;
            f32x4 (*acc)[4] = h ? acc1 : acc0;
            float bv[4];
#pragma unroll
            for (int j = 0; j < 4; ++j)
                bv[j] = lBias[e * 128 + wn * 64 + j * 16 + rA];
#pragma unroll
            for (int i = 0; i < 4; ++i) {
                int rb = wm * 64 + i * 16 + (lane >> 4) * 4;
                float g0 = lG[(rb + 0) * 8 + e];
                float g1 = lG[(rb + 1) * 8 + e];
                float g2 = lG[(rb + 2) * 8 + e];
                float g3 = lG[(rb + 3) * 8 + e];
#pragma unroll
                for (int j = 0; j < 4; ++j) {
                    outAcc[i][j].x += g0 * (acc[i][j].x + bv[j]);
                    outAcc[i][j].y += g1 * (acc[i][j].y + bv[j]);
                    outAcc[i][j].z += g2 * (acc[i][j].z + bv[j]);
                    outAcc[i][j].w += g3 * (acc[i][j].w + bv[j]);
                }
            }
        }
    }

    // epilogue: C layout col = lane&15, row = (lane>>4)*4 + reg
#pragma unroll
    for (int i = 0; i < 4; ++i) {
        int rowb = bm * 128 + wm * 64 + i * 16 + (lane >> 4) * 4;
#pragma unroll
        for (int j = 0; j < 4; ++j) {
            int col = bn * 128 + wn * 64 + j * 16 + rA;
            out[(size_t)(rowb + 0) * DOUT + col] = outAcc[i][j].x;
            out[(size_t)(rowb + 1) * DOUT + col] = outAcc[i][j].y;
            out[(size_t)(rowb + 2) * DOUT + col] = outAcc[i][j].z;
            out[(size_t)(rowb + 3) * DOUT + col] = outAcc[i][j].w;
        }
    }
}

// ---------------------------------------------------------------------------
extern "C" void kernel_launch(void* const* d_in, const int* in_sizes, int n_in,
                              void* d_out, int out_size, void* d_ws, size_t ws_size,
                              hipStream_t stream)
{
    const float* x  = (const float*)d_in[0];   // [8192,1024]
    const float* We = (const float*)d_in[1];   // [8,1024,1024]
    const float* be = (const float*)d_in[2];   // [8,1024]
    const float* Wg = (const float*)d_in[3];   // [1024,8]
    const float* bg = (const float*)d_in[4];   // [8]
    float* out = (float*)d_out;                // [8192,1024]

    // workspace: xb (16.78MB bf16) | WebT (16.78MB bf16) | g (256KB f32)
    unsigned short* xb = (unsigned short*)d_ws;
    unsigned short* wt = xb + (size_t)NTOK * DIN;
    float* g = (float*)(wt + (size_t)NEXP * DOUT * DIN);

    prep_kernel<<<2048 + 256, 256, 0, stream>>>(x, We, Wg, bg, xb, wt, g);
    moe_gemm_kernel<<<(NTOK / 128) * (DOUT / 128), 256, 0, stream>>>(xb, wt, g, be, out);
}

// Round 7
// 266.834 us; speedup vs baseline: 1.4377x; 1.4377x over previous
//
#include <hip/hip_runtime.h>
#include <hip/hip_bf16.h>
#include <cstdint>

// Problem constants
#define NTOK 8192
#define DIN  1024
#define DOUT 1024
#define NEXP 8

typedef __attribute__((ext_vector_type(8)))  __bf16 bf16x8;
typedef __attribute__((ext_vector_type(4)))  float  f32x4;

__device__ __forceinline__ unsigned short f2bf(float f) {
    unsigned int u = __builtin_bit_cast(unsigned int, f);
    u += 0x7FFFu + ((u >> 16) & 1u);   // round-to-nearest-even
    return (unsigned short)(u >> 16);
}

__device__ __forceinline__ void cp16(const void* gsrc, void* ldst) {
    __builtin_amdgcn_global_load_lds(
        (const __attribute__((address_space(1))) void*)gsrc,
        (__attribute__((address_space(3))) void*)ldst,
        16, 0, 0);
}

// ---------------------------------------------------------------------------
// Prep kernel (unchanged; non-GEMM time ~112us is harness-fixed — invariant
// across R1..R4's very different prep structures):
//   blocks [0, 2048):     We [e][k][o] fp32 -> WebT [e][o][k] bf16
//   blocks [2048, 2304):  gate softmax(x@Wg+bg) + x -> bf16
// ---------------------------------------------------------------------------
__global__ __launch_bounds__(256) void prep_kernel(
    const float* __restrict__ x, const float* __restrict__ We,
    const float* __restrict__ Wg, const float* __restrict__ bg,
    unsigned short* __restrict__ xb, unsigned short* __restrict__ wt,
    float* __restrict__ g)
{
    __shared__ float smem[12416];

    int t = threadIdx.x;

    if (blockIdx.x < 2048) {
        unsigned short* tile = (unsigned short*)smem;   // [64][72]
        int b = blockIdx.x;
        int e  = b >> 8;
        int kt = (b >> 4) & 15;
        int ot = b & 15;

        const float* src = We + ((size_t)e << 20) + (size_t)(kt * 64) * DOUT + ot * 64;
        unsigned short* dst = wt + ((size_t)e << 20) + (size_t)(ot * 64) * DIN + kt * 64;

        int kl = t >> 2;
        int og = (t & 3) * 16;
#pragma unroll
        for (int c = 0; c < 4; ++c) {
            int o = og + c * 4;
            float4 v = *(const float4*)&src[(size_t)kl * DOUT + o];
            ushort4 u;
            u.x = f2bf(v.x); u.y = f2bf(v.y); u.z = f2bf(v.z); u.w = f2bf(v.w);
            *(ushort4*)&tile[kl * 72 + o] = u;
        }
        __syncthreads();
        int ol = t >> 2;
        int kg = (t & 3) * 16;
        unsigned short tmp[16];
#pragma unroll
        for (int i = 0; i < 16; ++i) tmp[i] = tile[(kg + i) * 72 + ol];
        *(uint4*)&dst[(size_t)ol * DIN + kg]     = *(uint4*)&tmp[0];
        *(uint4*)&dst[(size_t)ol * DIN + kg + 8] = *(uint4*)&tmp[8];
    } else {
        float* WgL = smem;          // [8][1024] transposed Wg
        float* xL  = smem + 8192;   // [32][132] x chunk
        int n0 = (blockIdx.x - 2048) * 32;

#pragma unroll
        for (int q = 0; q < 8; ++q) {
            int fidx = q * 256 + t;
            int k  = fidx >> 1;
            int eh = (fidx & 1) * 4;
            float4 v = *(const float4*)&Wg[(size_t)k * 8 + eh];
            WgL[(eh + 0) * 1024 + k] = v.x;
            WgL[(eh + 1) * 1024 + k] = v.y;
            WgL[(eh + 2) * 1024 + k] = v.z;
            WgL[(eh + 3) * 1024 + k] = v.w;
        }

        int tt = t & 31;
        int e  = t >> 5;
        float acc = 0.f;

        for (int c = 0; c < 8; ++c) {
            int kb = c * 128;
#pragma unroll
            for (int q = 0; q < 4; ++q) {
                int fidx = q * 256 + t;
                int row = fidx >> 5;
                int kk  = (fidx & 31) * 4;
                float4 v = *(const float4*)&x[(size_t)(n0 + row) * DIN + kb + kk];
                ushort4 u;
                u.x = f2bf(v.x); u.y = f2bf(v.y); u.z = f2bf(v.z); u.w = f2bf(v.w);
                *(ushort4*)&xb[(size_t)(n0 + row) * DIN + kb + kk] = u;
                *(float4*)&xL[row * 132 + kk] = v;
            }
            __syncthreads();
#pragma unroll
            for (int kk = 0; kk < 128; kk += 4) {
                float4 xv = *(const float4*)&xL[tt * 132 + kk];
                float4 wv = *(const float4*)&WgL[e * 1024 + kb + kk];
                acc += xv.x * wv.x + xv.y * wv.y + xv.z * wv.z + xv.w * wv.w;
            }
            __syncthreads();
        }

        float* lg = xL;
        lg[tt * 8 + e] = acc + bg[e];
        __syncthreads();
        if (t < 32) {
            float l[8];
#pragma unroll
            for (int i = 0; i < 8; ++i) l[i] = lg[t * 8 + i];
            float m = l[0];
#pragma unroll
            for (int i = 1; i < 8; ++i) m = fmaxf(m, l[i]);
            float s = 0.f;
#pragma unroll
            for (int i = 0; i < 8; ++i) { l[i] = __expf(l[i] - m); s += l[i]; }
            float inv = 1.0f / s;
            float4 p0 = make_float4(l[0]*inv, l[1]*inv, l[2]*inv, l[3]*inv);
            float4 p1 = make_float4(l[4]*inv, l[5]*inv, l[6]*inv, l[7]*inv);
            *(float4*)&g[(size_t)(n0 + tt) * 8]     = p0;
            *(float4*)&g[(size_t)(n0 + tt) * 8 + 4] = p1;
        }
    }
}

// ---------------------------------------------------------------------------
// Main MoE GEMM — R2's verified geometry (16x16x32 MFMA, XOR k-chunk swizzle,
// XCD bm-slab) with BK=128 (R3's window size, MINUS R3's 32x32 fragment
// pattern whose reads 4-way bank-conflicted):
//  - barrier pairs per block: 128 -> 64 (drain amortized over 2x MFMA)
//  - bank check @ row stride 256B: row offset = 0 mod 32 banks; bank-group =
//    (kc mod 8) ^ (row&7); 16 rows -> each group hit exactly 2x = free (m136)
//  - LDS = lA+lB = 64KB exactly -> 2 blocks/CU; g/be read from global in the
//    per-expert merge (L1-hot, 8x per block)
//  - regs: acc+outAcc = 128 AGPR + ~110 VGPR < 256/wave unified cap at
//    launch_bounds(256,2)  [R4 lesson: 320 spilled -> 299MB scratch writes]
// R4's expert pairing reverted (structurally infeasible: 192 acc regs).
// ---------------------------------------------------------------------------
__global__ __launch_bounds__(256, 2) void moe_gemm_kernel(
    const unsigned short* __restrict__ xb,   // [NTOK][DIN] bf16
    const unsigned short* __restrict__ wt,   // [E][DOUT][DIN] bf16
    const float* __restrict__ g,             // [NTOK][E]
    const float* __restrict__ be,            // [E][DOUT]
    float* __restrict__ out)                 // [NTOK][DOUT]
{
    __shared__ unsigned short lA[128 * 128];   // 32 KB
    __shared__ unsigned short lB[128 * 128];   // 32 KB

    int bid = blockIdx.x;
    int bm = (bid & 7) * 8 + ((bid >> 3) & 7);   // 0..63, XCD-local A slab
    int bn = bid >> 6;                            // 0..7
    int tid = threadIdx.x;
    int lane = tid & 63;
    int wave = tid >> 6;
    int wm = wave >> 1;        // 0..1
    int wn = wave & 1;         // 0..1

    const unsigned short* aBase = xb + (size_t)(bm * 128) * DIN;
    const unsigned short* bBase0 = wt + (size_t)(bn * 128) * DIN;

    // staging geometry (verified in R3): instr s covers rows R0..R0+3,
    // R0 = s*16 + wave*4; lane covers (row R0+lrow, physical chunk cphys).
    // Physical chunk cphys holds logical chunk cphys ^ (row&7).
    int lrow  = lane >> 4;                           // 0..3
    int cphys = lane & 15;                           // physical 16B chunk
    int row7  = ((wave * 4) + lrow) & 7;             // (R0+lrow)&7
    int clog  = cphys ^ row7;                        // swizzled source chunk

    int rA   = lane & 15;                            // fragment row/col
    int quad = lane >> 4;                            // 0..3
    int swz  = rA & 7;

    f32x4 outAcc[4][4] = {};

#pragma unroll 1
    for (int e = 0; e < NEXP; ++e) {
        f32x4 acc[4][4] = {};
        const unsigned short* bBase = bBase0 + ((size_t)e << 20);

#pragma unroll 1
        for (int kt = 0; kt < 8; ++kt) {
            int kb = kt * 128;
            __syncthreads();
#pragma unroll
            for (int s = 0; s < 8; ++s) {
                int R0 = s * 16 + wave * 4;
                size_t srcOff = (size_t)(R0 + lrow) * DIN + kb + clog * 8;
                cp16(aBase + srcOff, &lA[R0 * 128]);
                cp16(bBase + srcOff, &lB[R0 * 128]);
            }
            __syncthreads();
#pragma unroll
            for (int ks = 0; ks < 4; ++ks) {
                int kc = ks * 4 + quad;               // logical chunk 0..15
                bf16x8 af[4], bfr[4];
#pragma unroll
                for (int i = 0; i < 4; ++i) {
                    int m = wm * 64 + i * 16 + rA;
                    af[i] = *(const bf16x8*)&lA[m * 128 + ((kc ^ swz)) * 8];
                }
#pragma unroll
                for (int j = 0; j < 4; ++j) {
                    int o = wn * 64 + j * 16 + rA;
                    bfr[j] = *(const bf16x8*)&lB[o * 128 + ((kc ^ swz)) * 8];
                }
#pragma unroll
                for (int i = 0; i < 4; ++i)
#pragma unroll
                    for (int j = 0; j < 4; ++j)
                        acc[i][j] = __builtin_amdgcn_mfma_f32_16x16x32_bf16(
                            af[i], bfr[j], acc[i][j], 0, 0, 0);
            }
        }

        // merge: outAcc += g[row,e] * (acc + be[e,col]); g/be L1-hot global
        float bv[4];
#pragma unroll
        for (int j = 0; j < 4; ++j)
            bv[j] = be[(size_t)e * DOUT + bn * 128 + wn * 64 + j * 16 + rA];
#pragma unroll
        for (int i = 0; i < 4; ++i) {
            int rbase = bm * 128 + wm * 64 + i * 16 + quad * 4;
            float g0 = g[(size_t)(rbase + 0) * 8 + e];
            float g1 = g[(size_t)(rbase + 1) * 8 + e];
            float g2 = g[(size_t)(rbase + 2) * 8 + e];
            float g3 = g[(size_t)(rbase + 3) * 8 + e];
#pragma unroll
            for (int j = 0; j < 4; ++j) {
                outAcc[i][j].x += g0 * (acc[i][j].x + bv[j]);
                outAcc[i][j].y += g1 * (acc[i][j].y + bv[j]);
                outAcc[i][j].z += g2 * (acc[i][j].z + bv[j]);
                outAcc[i][j].w += g3 * (acc[i][j].w + bv[j]);
            }
        }
    }

    // epilogue: C layout col = lane&15, row = quad*4 + reg
#pragma unroll
    for (int i = 0; i < 4; ++i) {
        int rowb = bm * 128 + wm * 64 + i * 16 + quad * 4;
#pragma unroll
        for (int j = 0; j < 4; ++j) {
            int col = bn * 128 + wn * 64 + j * 16 + rA;
            out[(size_t)(rowb + 0) * DOUT + col] = outAcc[i][j].x;
            out[(size_t)(rowb + 1) * DOUT + col] = outAcc[i][j].y;
            out[(size_t)(rowb + 2) * DOUT + col] = outAcc[i][j].z;
            out[(size_t)(rowb + 3) * DOUT + col] = outAcc[i][j].w;
        }
    }
}

// ---------------------------------------------------------------------------
extern "C" void kernel_launch(void* const* d_in, const int* in_sizes, int n_in,
                              void* d_out, int out_size, void* d_ws, size_t ws_size,
                              hipStream_t stream)
{
    const float* x  = (const float*)d_in[0];   // [8192,1024]
    const float* We = (const float*)d_in[1];   // [8,1024,1024]
    const float* be = (const float*)d_in[2];   // [8,1024]
    const float* Wg = (const float*)d_in[3];   // [1024,8]
    const float* bg = (const float*)d_in[4];   // [8]
    float* out = (float*)d_out;                // [8192,1024]

    // workspace: xb (16.78MB bf16) | WebT (16.78MB bf16) | g (256KB f32)
    unsigned short* xb = (unsigned short*)d_ws;
    unsigned short* wt = xb + (size_t)NTOK * DIN;
    float* g = (float*)(wt + (size_t)NEXP * DOUT * DIN);

    prep_kernel<<<2048 + 256, 256, 0, stream>>>(x, We, Wg, bg, xb, wt, g);
    moe_gemm_kernel<<<(NTOK / 128) * (DOUT / 128), 256, 0, stream>>>(xb, wt, g, be, out);
}

// Round 10
// 255.697 us; speedup vs baseline: 1.5003x; 1.0436x over previous
//
#include <hip/hip_runtime.h>
#include <hip/hip_bf16.h>
#include <cstdint>

// Problem constants
#define NTOK 8192
#define DIN  1024
#define DOUT 1024
#define NEXP 8

typedef __attribute__((ext_vector_type(8)))  __bf16 bf16x8;
typedef __attribute__((ext_vector_type(4)))  float  f32x4;

__device__ __forceinline__ unsigned short f2bf(float f) {
    unsigned int u = __builtin_bit_cast(unsigned int, f);
    u += 0x7FFFu + ((u >> 16) & 1u);   // round-to-nearest-even
    return (unsigned short)(u >> 16);
}

__device__ __forceinline__ void cp16(const void* gsrc, void* ldst) {
    __builtin_amdgcn_global_load_lds(
        (const __attribute__((address_space(1))) void*)gsrc,
        (__attribute__((address_space(3))) void*)ldst,
        16, 0, 0);
}

// ---------------------------------------------------------------------------
// Prep kernel (unchanged; non-GEMM time ~112us is harness-fixed — invariant
// across R1..R7's very different prep structures):
//   blocks [0, 2048):     We [e][k][o] fp32 -> WebT [e][o][k] bf16
//   blocks [2048, 2304):  gate softmax(x@Wg+bg) + x -> bf16
// ---------------------------------------------------------------------------
__global__ __launch_bounds__(256) void prep_kernel(
    const float* __restrict__ x, const float* __restrict__ We,
    const float* __restrict__ Wg, const float* __restrict__ bg,
    unsigned short* __restrict__ xb, unsigned short* __restrict__ wt,
    float* __restrict__ g)
{
    __shared__ float smem[12416];

    int t = threadIdx.x;

    if (blockIdx.x < 2048) {
        unsigned short* tile = (unsigned short*)smem;   // [64][72]
        int b = blockIdx.x;
        int e  = b >> 8;
        int kt = (b >> 4) & 15;
        int ot = b & 15;

        const float* src = We + ((size_t)e << 20) + (size_t)(kt * 64) * DOUT + ot * 64;
        unsigned short* dst = wt + ((size_t)e << 20) + (size_t)(ot * 64) * DIN + kt * 64;

        int kl = t >> 2;
        int og = (t & 3) * 16;
#pragma unroll
        for (int c = 0; c < 4; ++c) {
            int o = og + c * 4;
            float4 v = *(const float4*)&src[(size_t)kl * DOUT + o];
            ushort4 u;
            u.x = f2bf(v.x); u.y = f2bf(v.y); u.z = f2bf(v.z); u.w = f2bf(v.w);
            *(ushort4*)&tile[kl * 72 + o] = u;
        }
        __syncthreads();
        int ol = t >> 2;
        int kg = (t & 3) * 16;
        unsigned short tmp[16];
#pragma unroll
        for (int i = 0; i < 16; ++i) tmp[i] = tile[(kg + i) * 72 + ol];
        *(uint4*)&dst[(size_t)ol * DIN + kg]     = *(uint4*)&tmp[0];
        *(uint4*)&dst[(size_t)ol * DIN + kg + 8] = *(uint4*)&tmp[8];
    } else {
        float* WgL = smem;          // [8][1024] transposed Wg
        float* xL  = smem + 8192;   // [32][132] x chunk
        int n0 = (blockIdx.x - 2048) * 32;

#pragma unroll
        for (int q = 0; q < 8; ++q) {
            int fidx = q * 256 + t;
            int k  = fidx >> 1;
            int eh = (fidx & 1) * 4;
            float4 v = *(const float4*)&Wg[(size_t)k * 8 + eh];
            WgL[(eh + 0) * 1024 + k] = v.x;
            WgL[(eh + 1) * 1024 + k] = v.y;
            WgL[(eh + 2) * 1024 + k] = v.z;
            WgL[(eh + 3) * 1024 + k] = v.w;
        }

        int tt = t & 31;
        int e  = t >> 5;
        float acc = 0.f;

        for (int c = 0; c < 8; ++c) {
            int kb = c * 128;
#pragma unroll
            for (int q = 0; q < 4; ++q) {
                int fidx = q * 256 + t;
                int row = fidx >> 5;
                int kk  = (fidx & 31) * 4;
                float4 v = *(const float4*)&x[(size_t)(n0 + row) * DIN + kb + kk];
                ushort4 u;
                u.x = f2bf(v.x); u.y = f2bf(v.y); u.z = f2bf(v.z); u.w = f2bf(v.w);
                *(ushort4*)&xb[(size_t)(n0 + row) * DIN + kb + kk] = u;
                *(float4*)&xL[row * 132 + kk] = v;
            }
            __syncthreads();
#pragma unroll
            for (int kk = 0; kk < 128; kk += 4) {
                float4 xv = *(const float4*)&xL[tt * 132 + kk];
                float4 wv = *(const float4*)&WgL[e * 1024 + kb + kk];
                acc += xv.x * wv.x + xv.y * wv.y + xv.z * wv.z + xv.w * wv.w;
            }
            __syncthreads();
        }

        float* lg = xL;
        lg[tt * 8 + e] = acc + bg[e];
        __syncthreads();
        if (t < 32) {
            float l[8];
#pragma unroll
            for (int i = 0; i < 8; ++i) l[i] = lg[t * 8 + i];
            float m = l[0];
#pragma unroll
            for (int i = 1; i < 8; ++i) m = fmaxf(m, l[i]);
            float s = 0.f;
#pragma unroll
            for (int i = 0; i < 8; ++i) { l[i] = __expf(l[i] - m); s += l[i]; }
            float inv = 1.0f / s;
            float4 p0 = make_float4(l[0]*inv, l[1]*inv, l[2]*inv, l[3]*inv);
            float4 p1 = make_float4(l[4]*inv, l[5]*inv, l[6]*inv, l[7]*inv);
            *(float4*)&g[(size_t)(n0 + tt) * 8]     = p0;
            *(float4*)&g[(size_t)(n0 + tt) * 8 + 4] = p1;
        }
    }
}

// ---------------------------------------------------------------------------
// Main MoE GEMM — BK=128 windows (64 barrier-pairs, R7's amortization) built
// from TWO 128B-stride BK=64 sub-buffers each for A and B (R2's verified
// conflict-free read pattern). Measured rule (R2/R3/R7): b128 fragment reads
// from 256B-strided LDS rows cost exactly 4 conflict-cyc/read regardless of
// swizzle (R3=R7=2^24 exactly); 128B stride + XOR swizzle is free (R2=2^19).
// Structurally perturbed vs the R8/R9 source (separate flat arrays, manual
// h-unroll) to dodge any deterministic toolchain trigger; semantics and LDS
// byte layout identical.
//  - lA0+lA1+lB0+lB1 = 64 KB -> 2 blocks/CU
//  - staging: 16 cp16/thread/window; dest wave-uniform base + lane*16
//  - fragment reads byte-identical to R2's measured-free pattern
//  - merge reads g/be from global (L1-hot; FETCH stayed 86 MB in R7)
//  - regs ~128 VGPR + 128 acc < 256/wave unified cap (R4 spill lesson)
// ---------------------------------------------------------------------------
__global__ __launch_bounds__(256, 2) void moe_gemm_kernel(
    const unsigned short* __restrict__ xb,   // [NTOK][DIN] bf16
    const unsigned short* __restrict__ wt,   // [E][DOUT][DIN] bf16
    const float* __restrict__ g,             // [NTOK][E]
    const float* __restrict__ be,            // [E][DOUT]
    float* __restrict__ out)                 // [NTOK][DOUT]
{
    __shared__ unsigned short lA0[128 * 64];   // 16 KB, k in [0,64)
    __shared__ unsigned short lA1[128 * 64];   // 16 KB, k in [64,128)
    __shared__ unsigned short lB0[128 * 64];
    __shared__ unsigned short lB1[128 * 64];

    int bid = blockIdx.x;
    int bm = (bid & 7) * 8 + ((bid >> 3) & 7);   // 0..63, XCD-local A slab
    int bn = bid >> 6;                            // 0..7
    int tid = threadIdx.x;
    int lane = tid & 63;
    int wave = tid >> 6;
    int wm = wave >> 1;        // 0..1
    int wn = wave & 1;         // 0..1

    const unsigned short* aBase = xb + (size_t)(bm * 128) * DIN;
    const unsigned short* bBase0 = wt + (size_t)(bn * 128) * DIN;

    // R2 staging geometry per sub-buffer: lane covers (row rowS+32j, physical
    // chunk lane&7); physical chunk holds logical chunk (lane&7)^(row&7).
    int rowS = wave * 8 + (lane >> 3);                    // row in 32-row group
    int k8   = (((lane & 7) ^ (lane >> 3)) * 8);          // swizzled source k
    int rA   = lane & 15;                                 // fragment row/col
    int quad = lane >> 4;                                 // 0..3
    int swz  = rA & 7;

    f32x4 outAcc[4][4] = {};

#pragma unroll 1
    for (int e = 0; e < NEXP; ++e) {
        f32x4 acc[4][4] = {};
        const unsigned short* bBase = bBase0 + ((size_t)e << 20);

#pragma unroll 1
        for (int kt = 0; kt < 8; ++kt) {
            int kb = kt * 128;
            __syncthreads();
#pragma unroll
            for (int j = 0; j < 4; ++j) {
                int row = j * 32 + rowS;
                size_t so0 = (size_t)row * DIN + kb + k8;
                size_t so1 = so0 + 64;
                int dst = j * 2048 + wave * 512;
                cp16(aBase + so0, &lA0[dst]);
                cp16(aBase + so1, &lA1[dst]);
                cp16(bBase + so0, &lB0[dst]);
                cp16(bBase + so1, &lB1[dst]);
            }
            __syncthreads();
#pragma unroll
            for (int ks = 0; ks < 2; ++ks) {
                int kc = ks * 4 + quad;               // logical chunk 0..7
                int kp = (kc ^ swz) * 8;              // swizzled offset
                bf16x8 af[4], bfr[4];
                // ---- half 0: k in [0,64) ----
#pragma unroll
                for (int i = 0; i < 4; ++i)
                    af[i] = *(const bf16x8*)&lA0[(wm * 64 + i * 16 + rA) * 64 + kp];
#pragma unroll
                for (int j = 0; j < 4; ++j)
                    bfr[j] = *(const bf16x8*)&lB0[(wn * 64 + j * 16 + rA) * 64 + kp];
#pragma unroll
                for (int i = 0; i < 4; ++i)
#pragma unroll
                    for (int j = 0; j < 4; ++j)
                        acc[i][j] = __builtin_amdgcn_mfma_f32_16x16x32_bf16(
                            af[i], bfr[j], acc[i][j], 0, 0, 0);
                // ---- half 1: k in [64,128) ----
#pragma unroll
                for (int i = 0; i < 4; ++i)
                    af[i] = *(const bf16x8*)&lA1[(wm * 64 + i * 16 + rA) * 64 + kp];
#pragma unroll
                for (int j = 0; j < 4; ++j)
                    bfr[j] = *(const bf16x8*)&lB1[(wn * 64 + j * 16 + rA) * 64 + kp];
#pragma unroll
                for (int i = 0; i < 4; ++i)
#pragma unroll
                    for (int j = 0; j < 4; ++j)
                        acc[i][j] = __builtin_amdgcn_mfma_f32_16x16x32_bf16(
                            af[i], bfr[j], acc[i][j], 0, 0, 0);
            }
        }

        // merge: outAcc += g[row,e] * (acc + be[e,col]); g/be L1-hot global
        float bv[4];
#pragma unroll
        for (int j = 0; j < 4; ++j)
            bv[j] = be[(size_t)e * DOUT + bn * 128 + wn * 64 + j * 16 + rA];
#pragma unroll
        for (int i = 0; i < 4; ++i) {
            int rbase = bm * 128 + wm * 64 + i * 16 + quad * 4;
            float g0 = g[(size_t)(rbase + 0) * 8 + e];
            float g1 = g[(size_t)(rbase + 1) * 8 + e];
            float g2 = g[(size_t)(rbase + 2) * 8 + e];
            float g3 = g[(size_t)(rbase + 3) * 8 + e];
#pragma unroll
            for (int j = 0; j < 4; ++j) {
                outAcc[i][j].x += g0 * (acc[i][j].x + bv[j]);
                outAcc[i][j].y += g1 * (acc[i][j].y + bv[j]);
                outAcc[i][j].z += g2 * (acc[i][j].z + bv[j]);
                outAcc[i][j].w += g3 * (acc[i][j].w + bv[j]);
            }
        }
    }

    // epilogue: C layout col = lane&15, row = quad*4 + reg
#pragma unroll
    for (int i = 0; i < 4; ++i) {
        int rowb = bm * 128 + wm * 64 + i * 16 + quad * 4;
#pragma unroll
        for (int j = 0; j < 4; ++j) {
            int col = bn * 128 + wn * 64 + j * 16 + rA;
            out[(size_t)(rowb + 0) * DOUT + col] = outAcc[i][j].x;
            out[(size_t)(rowb + 1) * DOUT + col] = outAcc[i][j].y;
            out[(size_t)(rowb + 2) * DOUT + col] = outAcc[i][j].z;
            out[(size_t)(rowb + 3) * DOUT + col] = outAcc[i][j].w;
        }
    }
}

// ---------------------------------------------------------------------------
extern "C" void kernel_launch(void* const* d_in, const int* in_sizes, int n_in,
                              void* d_out, int out_size, void* d_ws, size_t ws_size,
                              hipStream_t stream)
{
    const float* x  = (const float*)d_in[0];   // [8192,1024]
    const float* We = (const float*)d_in[1];   // [8,1024,1024]
    const float* be = (const float*)d_in[2];   // [8,1024]
    const float* Wg = (const float*)d_in[3];   // [1024,8]
    const float* bg = (const float*)d_in[4];   // [8]
    float* out = (float*)d_out;                // [8192,1024]

    // workspace: xb (16.78MB bf16) | WebT (16.78MB bf16) | g (256KB f32)
    unsigned short* xb = (unsigned short*)d_ws;
    unsigned short* wt = xb + (size_t)NTOK * DIN;
    float* g = (float*)(wt + (size_t)NEXP * DOUT * DIN);

    prep_kernel<<<2048 + 256, 256, 0, stream>>>(x, We, Wg, bg, xb, wt, g);
    moe_gemm_kernel<<<(NTOK / 128) * (DOUT / 128), 256, 0, stream>>>(xb, wt, g, be, out);
}